// Round 8
// baseline (166.434 us; speedup 1.0000x reference)
//
#include <hip/hip_runtime.h>
#include <math.h>

// SS2D (VMamba v2) forward — MI355X gfx950.
// 6 dispatches. R8 = R7 config with ONE change: k_inproj3's B-operand loads
// are explicitly double-buffered (R2 profile: VGPR=24 -> compiler serialized
// 36 L2 loads/wave; 17.8us vs ~5us roofline). MFMA order per accumulator is
// unchanged -> bit-identical xin/zb.
//  k_castW   : W_in -> (hi,lo); xpw -> (hi,lo, 48-row padded); W_out -> bf16
//  k_inproj3 : xz = x @ W_in^T via bf16x3 MFMA (16-px, B-prefetch)  [R8]
//  k_conv8   : depthwise 3x3 + bias + silu -> xg               [proven]
//  k_xscan   : fused x_dbl MFMA + local scan -> yout/Qb/Sbuf + dtr/Cm [proven R5]
//  k_scan3p  : correction with chunk-prefix folded in          [proven R7]
//  k_lnout   : merge + LayerNorm + gate -> MFMA out GEMM       [proven]

#define DINNER 192
#define NSTATE 16
#define KDIR 4
#define BATCH 4
#define NPIX (BATCH * 64 * 64)          // 16384
#define LP 1024
#define NCH 64                          // scan chunks
#define CHUNK 16                        // LP / NCH
#define NBK (BATCH * KDIR)              // 16
#define NSTATES (NBK * DINNER * NSTATE) // 49152
#define SSTRIDE (NBK * DINNER)          // 3072 floats of S per chunk
#define USTRIDE 196                     // scan sU row stride (floats)
#define GSTRIDE 200                     // lnout bf16 g LDS stride (shorts)
#define ASTRIDE 104                     // inproj LDS A stride (shorts, 96 padded)
#define XSTRIDE 200                     // xdbl LDS A stride (shorts, 192 padded)

typedef __attribute__((ext_vector_type(8))) short short8;
typedef __attribute__((ext_vector_type(4))) short short4v;
typedef __attribute__((ext_vector_type(4))) unsigned short ushort4v;
typedef __attribute__((ext_vector_type(8))) unsigned short ushort8v;
typedef __attribute__((ext_vector_type(4))) float f32x4;

__device__ __forceinline__ float silu_f(float x) {
    return x / (1.0f + __expf(-x));
}
__device__ __forceinline__ float softplus_f(float a) {
    return (a > 20.0f) ? a : __logf(1.0f + __expf(a));
}
__device__ __forceinline__ unsigned short f2bf(float f) {
    unsigned u = __float_as_uint(f);
    unsigned r = (u + 0x7FFFu + ((u >> 16) & 1u)) >> 16;
    return (unsigned short)r;
}
__device__ __forceinline__ float bf2f(unsigned short h) {
    return __uint_as_float(((unsigned)h) << 16);
}

// Weights: W_in hi/lo split; xpw hi/lo split into 48-row padded layout
// (rows 38..47 zero); W_out bf16 cast.
__global__ __launch_bounds__(256) void k_castW(
        const float* __restrict__ W_in, const float* __restrict__ xpw,
        const float* __restrict__ W_out,
        unsigned short* __restrict__ Wi_hi, unsigned short* __restrict__ Wi_lo,
        unsigned short* __restrict__ Xp_hi, unsigned short* __restrict__ Xp_lo,
        unsigned short* __restrict__ Wo_bf) {
    int i = blockIdx.x * 256 + threadIdx.x;
    if (i < 384 * 96) {
        float v = W_in[i];
        unsigned short h = f2bf(v);
        Wi_hi[i] = h;
        Wi_lo[i] = f2bf(v - bf2f(h));
    }
    if (i < 4 * 48 * 192) {           // padded xpw split
        int kk = i / (48 * 192);
        int rem = i - kk * (48 * 192);
        int c = rem / 192;
        int j = rem - c * 192;
        float v = (c < 38) ? xpw[((size_t)kk * 38 + c) * 192 + j] : 0.0f;
        unsigned short h = f2bf(v);
        Xp_hi[i] = h;
        Xp_lo[i] = f2bf(v - bf2f(h));
    }
    if (i < 96 * DINNER) Wo_bf[i] = f2bf(W_out[i]);
}

// MFMA in-proj (bf16x3 split); x split staged ONCE in LDS (shared by 4 waves).
// R8: B-operand (weight) fragments double-buffered in registers so the 36
// L2 loads per wave pipeline instead of serializing (was VGPR=24 -> ~4 in
// flight). MFMA sequence per accumulator unchanged -> bit-identical output.
__global__ __launch_bounds__(256) void k_inproj3(
        const float* __restrict__ x,
        const unsigned short* __restrict__ Wi_hi,
        const unsigned short* __restrict__ Wi_lo,
        float* __restrict__ xin, unsigned short* __restrict__ zb) {
    __shared__ __align__(16) short sAh[16 * ASTRIDE];
    __shared__ __align__(16) short sAl[16 * ASTRIDE];
    int p0 = blockIdx.x * 16;
    int t = threadIdx.x;
    const float4* xs = (const float4*)(x + (size_t)p0 * 96);
    for (int i = t; i < 384; i += 256) {     // 16*96 floats = 384 float4
        float4 v = xs[i];
        int f = i * 4;
        int row = f / 96, col = f - row * 96;
        short4v hi, lo;
        unsigned short hb;
        hb = f2bf(v.x); hi.x = (short)hb; lo.x = (short)f2bf(v.x - bf2f(hb));
        hb = f2bf(v.y); hi.y = (short)hb; lo.y = (short)f2bf(v.y - bf2f(hb));
        hb = f2bf(v.z); hi.z = (short)hb; lo.z = (short)f2bf(v.z - bf2f(hb));
        hb = f2bf(v.w); hi.w = (short)hb; lo.w = (short)f2bf(v.w - bf2f(hb));
        *(short4v*)&sAh[row * ASTRIDE + col] = hi;
        *(short4v*)&sAl[row * ASTRIDE + col] = lo;
    }
    __syncthreads();
    int w = t >> 6;
    int lane = t & 63;
    int m = lane & 15, quad = lane >> 4;
    const short* wh = (const short*)Wi_hi;
    const short* wl = (const short*)Wi_lo;
    short8 ah[3], al[3];
    #pragma unroll
    for (int c = 0; c < 3; ++c) {
        ah[c] = *(const short8*)&sAh[m * ASTRIDE + c * 32 + quad * 8];
        al[c] = *(const short8*)&sAl[m * ASTRIDE + c * 32 + quad * 8];
    }
    // ---- B double-buffer: bank A holds even-i fragments, bank B odd-i ----
    short8 bhA[3], blA[3], bhB[3], blB[3];
    {
        size_t o0 = (size_t)((w * 6 + 0) * 16 + m) * 96 + quad * 8;
        #pragma unroll
        for (int c = 0; c < 3; ++c) {
            bhA[c] = *(const short8*)(wh + o0 + c * 32);
            blA[c] = *(const short8*)(wl + o0 + c * 32);
        }
    }
    #pragma unroll
    for (int i = 0; i < 6; ++i) {
        // issue next-i loads before this i's MFMAs (hide L2 latency)
        if (i < 5) {
            size_t on = (size_t)((w * 6 + i + 1) * 16 + m) * 96 + quad * 8;
            if (i & 1) {
                #pragma unroll
                for (int c = 0; c < 3; ++c) {
                    bhA[c] = *(const short8*)(wh + on + c * 32);
                    blA[c] = *(const short8*)(wl + on + c * 32);
                }
            } else {
                #pragma unroll
                for (int c = 0; c < 3; ++c) {
                    bhB[c] = *(const short8*)(wh + on + c * 32);
                    blB[c] = *(const short8*)(wl + on + c * 32);
                }
            }
        }
        f32x4 acc = {0.f, 0.f, 0.f, 0.f};
        if (i & 1) {
            #pragma unroll
            for (int c = 0; c < 3; ++c) {
                acc = __builtin_amdgcn_mfma_f32_16x16x32_bf16(ah[c], blB[c], acc, 0, 0, 0);
                acc = __builtin_amdgcn_mfma_f32_16x16x32_bf16(al[c], bhB[c], acc, 0, 0, 0);
                acc = __builtin_amdgcn_mfma_f32_16x16x32_bf16(ah[c], bhB[c], acc, 0, 0, 0);
            }
        } else {
            #pragma unroll
            for (int c = 0; c < 3; ++c) {
                acc = __builtin_amdgcn_mfma_f32_16x16x32_bf16(ah[c], blA[c], acc, 0, 0, 0);
                acc = __builtin_amdgcn_mfma_f32_16x16x32_bf16(al[c], bhA[c], acc, 0, 0, 0);
                acc = __builtin_amdgcn_mfma_f32_16x16x32_bf16(ah[c], bhA[c], acc, 0, 0, 0);
            }
        }
        int e = (w * 6 + i) * 16 + m;
        #pragma unroll
        for (int r = 0; r < 4; ++r) {
            int p = p0 + quad * 4 + r;
            if (e < 192) xin[(size_t)p * 192 + e] = acc[r];
            else         zb[(size_t)p * 192 + (e - 192)] = f2bf(silu_f(acc[r]));
        }
    }
}

// depthwise 3x3, 8 pixels/block; full 3x10 window preloaded into registers.
__global__ __launch_bounds__(192) void k_conv8(
        const float* __restrict__ xin, const float* __restrict__ cw,
        const float* __restrict__ cb, float* __restrict__ xg) {
    int blk = blockIdx.x;             // 2048 = 4 b * 64 h * 8 wchunks
    int b = blk >> 9;
    int rem = blk & 511;
    int h = rem >> 3;
    int w0 = (rem & 7) * 8;
    int d = threadIdx.x;
    float wr[3][3];
    #pragma unroll
    for (int i = 0; i < 3; ++i)
        #pragma unroll
        for (int j = 0; j < 3; ++j) wr[i][j] = cw[d * 9 + i * 3 + j];
    float bias = cb[d];
    float r0[10], r1[10], r2[10];
    #pragma unroll
    for (int jj = 0; jj < 10; ++jj) {
        int ww = w0 + jj - 1;
        bool inw = (unsigned)ww < 64u;        // block-uniform
        const float* base = xin + ((size_t)b * 4096 + h * 64 + (inw ? ww : 0)) * 192 + d;
        r0[jj] = (inw && h > 0)  ? base[-64 * 192] : 0.0f;
        r1[jj] = inw             ? base[0]         : 0.0f;
        r2[jj] = (inw && h < 63) ? base[64 * 192]  : 0.0f;
    }
    float acc[8];
    #pragma unroll
    for (int o = 0; o < 8; ++o) {
        float a = bias;
        #pragma unroll
        for (int j = 0; j < 3; ++j) {
            a = fmaf(r0[o + j], wr[0][j], a);
            a = fmaf(r1[o + j], wr[1][j], a);
            a = fmaf(r2[o + j], wr[2][j], a);
        }
        acc[o] = a;
    }
    #pragma unroll
    for (int o = 0; o < 8; ++o) {
        int w = w0 + o;
        int kq = (h & 1) ? ((w & 1) ? 3 : 1) : ((w & 1) ? 2 : 0);
        int l = (kq & 1) ? ((w >> 1) * 32 + (h >> 1))
                         : ((h >> 1) * 32 + (w >> 1));
        xg[((size_t)(b * 4 + kq) * 1024 + l) * 192 + d] = silu_f(acc[o]);
    }
}

// Fused x_dbl MFMA + local scan (h_in = 0). [proven R5]
__global__ __launch_bounds__(192) void k_xscan(
        const float* __restrict__ xg,
        const unsigned short* __restrict__ Xp_hi,
        const unsigned short* __restrict__ Xp_lo,
        const float* __restrict__ A_logs, const float* __restrict__ dtw,
        const float* __restrict__ dtb, const float* __restrict__ Ds,
        float* __restrict__ dtr, float* __restrict__ Cm,
        float* __restrict__ Sbuf, unsigned short* __restrict__ Qb,
        unsigned short* __restrict__ yout) {
    __shared__ __align__(16) short sAh[16 * XSTRIDE];
    __shared__ __align__(16) short sAl[16 * XSTRIDE];
    __shared__ __align__(16) float sU[CHUNK * USTRIDE];
    __shared__ float sB[CHUNK * 16];
    __shared__ float sC[CHUNK * 16];
    __shared__ float sDt[CHUNK * 6];

    int bk = blockIdx.x >> 6;
    int ch = blockIdx.x & 63;
    int k = bk & 3;
    int t = threadIdx.x;
    int d = t;
    int lbase = bk * 1024 + ch * CHUNK;

    // ---- stage u tile: fp32 sU + bf16 hi/lo split ----
    {
        const float4* us = (const float4*)(xg + (size_t)lbase * 192);
        for (int i = t; i < 768; i += 192) {     // 16*192 floats = 768 float4
            float4 v = us[i];
            int f = i * 4;
            int row = f / 192, col = f - row * 192;
            short4v hi, lo;
            unsigned short hb;
            hb = f2bf(v.x); hi.x = (short)hb; lo.x = (short)f2bf(v.x - bf2f(hb));
            hb = f2bf(v.y); hi.y = (short)hb; lo.y = (short)f2bf(v.y - bf2f(hb));
            hb = f2bf(v.z); hi.z = (short)hb; lo.z = (short)f2bf(v.z - bf2f(hb));
            hb = f2bf(v.w); hi.w = (short)hb; lo.w = (short)f2bf(v.w - bf2f(hb));
            *(short4v*)&sAh[row * XSTRIDE + col] = hi;
            *(short4v*)&sAl[row * XSTRIDE + col] = lo;
            *(float4*)&sU[row * USTRIDE + col] = v;
        }
    }
    __syncthreads();

    // ---- x_dbl MFMA (k_xdbl body), stores -> sDt/sB/sC ----
    {
        int wv = t >> 6;                  // N-tile 0..2
        int lane = t & 63;
        int m = lane & 15, quad = lane >> 4;
        const short* bh16 = (const short*)Xp_hi;
        const short* bl16 = (const short*)Xp_lo;
        int n0 = wv * 16;
        size_t brow = ((size_t)k * 48 + n0 + m) * 192;
        f32x4 acc = {0.f, 0.f, 0.f, 0.f};
        #pragma unroll
        for (int c = 0; c < 6; ++c) {
            short8 ah = *(const short8*)&sAh[m * XSTRIDE + c * 32 + quad * 8];
            short8 al = *(const short8*)&sAl[m * XSTRIDE + c * 32 + quad * 8];
            short8 bh = *(const short8*)(bh16 + brow + c * 32 + quad * 8);
            short8 bl = *(const short8*)(bl16 + brow + c * 32 + quad * 8);
            acc = __builtin_amdgcn_mfma_f32_16x16x32_bf16(ah, bl, acc, 0, 0, 0);
            acc = __builtin_amdgcn_mfma_f32_16x16x32_bf16(al, bh, acc, 0, 0, 0);
            acc = __builtin_amdgcn_mfma_f32_16x16x32_bf16(ah, bh, acc, 0, 0, 0);
        }
        int c = n0 + m;                   // output c-row
        #pragma unroll
        for (int r = 0; r < 4; ++r) {
            int ll = quad * 4 + r;
            float v = acc[r];
            if (c < 6)       sDt[ll * 6 + c] = v;
            else if (c < 22) sB[ll * 16 + (c - 6)] = v;
            else if (c < 38) sC[ll * 16 + (c - 22)] = v;
        }
    }
    __syncthreads();

    // ---- dump dtr / Cm for k_scan3p ----
    if (t < 96) dtr[(size_t)(lbase + t / 6) * 6 + (t % 6)] = sDt[t];
    for (int i = t; i < CHUNK * 16; i += 192)
        Cm[(size_t)lbase * 16 + i] = sC[i];

    // ---- local scan (k_scan1y body; dlt from sDt, u from fp32 sU) ----
    {
        float A[16];
        #pragma unroll
        for (int n = 0; n < 16; ++n) A[n] = -__expf(A_logs[(k * 192 + d) * 16 + n]);
        float A0 = A[0];
        bool geo = true;                 // A[n] == (n+1)*A[0] (geometric ladder)?
        #pragma unroll
        for (int n = 1; n < 16; ++n)
            geo = geo && (fabsf(A[n] - (float)(n + 1) * A0) <= 1e-4f * fabsf(A[n]));
        float wp[6];
        #pragma unroll
        for (int q = 0; q < 6; ++q) wp[q] = dtw[(k * 192 + d) * 6 + q];
        float bias = dtb[k * 192 + d];
        float Dp = Ds[k * 192 + d];
        float dlt[CHUNK];
        #pragma unroll 4
        for (int l = 0; l < CHUNK; ++l) {
            float a = bias;
            #pragma unroll
            for (int q = 0; q < 6; ++q) a = fmaf(wp[q], sDt[l * 6 + q], a);
            dlt[l] = softplus_f(a);
        }
        float S = 0.0f;
        #pragma unroll
        for (int l = 0; l < CHUNK; ++l) S += dlt[l];
        float h[16];
        #pragma unroll
        for (int n = 0; n < 16; ++n) h[n] = 0.0f;
        if (geo) {
            float e1v[CHUNK];
            #pragma unroll 4
            for (int l = 0; l < CHUNK; ++l) e1v[l] = __expf(dlt[l] * A0);
            #pragma unroll 2
            for (int l = 0; l < CHUNK; ++l) {
                float u = sU[l * USTRIDE + d];
                float du = dlt[l] * u;
                float e1 = e1v[l];
                float e = e1;
                float y = 0.0f;
                #pragma unroll
                for (int n = 0; n < 16; ++n) {
                    h[n] = fmaf(e, h[n], du * sB[l * 16 + n]);
                    y = fmaf(h[n], sC[l * 16 + n], y);
                    e *= e1;
                }
                yout[(size_t)(lbase + l) * 192 + d] = f2bf(fmaf(u, Dp, y));
            }
        } else {
            for (int l = 0; l < CHUNK; ++l) {
                float u = sU[l * USTRIDE + d];
                float du = dlt[l] * u;
                float y = 0.0f;
                #pragma unroll
                for (int n = 0; n < 16; ++n) {
                    float e = __expf(dlt[l] * A[n]);
                    h[n] = fmaf(e, h[n], du * sB[l * 16 + n]);
                    y = fmaf(h[n], sC[l * 16 + n], y);
                }
                yout[(size_t)(lbase + l) * 192 + d] = f2bf(fmaf(u, Dp, y));
            }
        }
        Sbuf[(size_t)ch * SSTRIDE + bk * 192 + d] = S;
        size_t base = (size_t)ch * NSTATES + bk * (192 * 16);
        #pragma unroll
        for (int n = 0; n < 16; ++n)
            Qb[base + n * 192 + d] = f2bf(h[n]);
    }
}

// Chain-free correction with the chunk-prefix folded in (replaces k_scan2).
// h0 computed per block from Sbuf/Qb via the scan2 recurrence
// (h <- exp(A*S_c)*h + q_c for c = 0..ch-1); correction body = scan3c verbatim.
__global__ __launch_bounds__(192) void k_scan3p(
        const float* __restrict__ dtr, const float* __restrict__ Cm,
        const float* __restrict__ A_logs, const float* __restrict__ dtw,
        const float* __restrict__ dtb,
        const float* __restrict__ Sbuf, const unsigned short* __restrict__ Qb,
        unsigned short* __restrict__ yout) {
    __shared__ float sC[CHUNK * 16];
    int bk = blockIdx.x >> 6;
    int ch = blockIdx.x & 63;
    if (ch == 0) return;              // h0 == 0, no correction
    int k = bk & 3;
    int d = threadIdx.x;
    int lbase = bk * 1024 + ch * CHUNK;
    for (int i = d; i < CHUNK * 16; i += 192)
        sC[i] = Cm[(size_t)lbase * 16 + i];
    float A[16];
    #pragma unroll
    for (int n = 0; n < 16; ++n) A[n] = -__expf(A_logs[(k * 192 + d) * 16 + n]);
    float A0 = A[0];
    bool geo = true;
    #pragma unroll
    for (int n = 1; n < 16; ++n)
        geo = geo && (fabsf(A[n] - (float)(n + 1) * A0) <= 1e-4f * fabsf(A[n]));
    float wp[6];
    #pragma unroll
    for (int q = 0; q < 6; ++q) wp[q] = dtw[(k * 192 + d) * 6 + q];
    float bias = dtb[k * 192 + d];

    // ---- h0 prefix over chunks 0..ch-1 (was k_scan2 + Hst) ----
    float h0[16];
    #pragma unroll
    for (int n = 0; n < 16; ++n) h0[n] = 0.0f;
    {
        int sb = bk * 192 + d;
        size_t qoff = (size_t)bk * 3072 + d;
        if (geo) {
            for (int c = 0; c < ch; ++c) {
                float Sv = Sbuf[(size_t)c * SSTRIDE + sb];
                float e1 = __expf(A0 * Sv);
                float e = e1;
                const unsigned short* qrow = Qb + (size_t)c * NSTATES + qoff;
                #pragma unroll
                for (int n = 0; n < 16; ++n) {
                    h0[n] = fmaf(e, h0[n], bf2f(qrow[n * 192]));
                    e *= e1;
                }
            }
        } else {
            for (int c = 0; c < ch; ++c) {
                float Sv = Sbuf[(size_t)c * SSTRIDE + sb];
                const unsigned short* qrow = Qb + (size_t)c * NSTATES + qoff;
                #pragma unroll
                for (int n = 0; n < 16; ++n)
                    h0[n] = fmaf(__expf(A[n] * Sv), h0[n], bf2f(qrow[n * 192]));
            }
        }
    }

    float Sarr[CHUNK];
    {
        float S = 0.0f;
        #pragma unroll 4
        for (int l = 0; l < CHUNK; ++l) {
            const float* r = dtr + (size_t)(lbase + l) * 6;   // wave-uniform
            float a = bias;
            #pragma unroll
            for (int q = 0; q < 6; ++q) a = fmaf(wp[q], r[q], a);
            S += softplus_f(a);
            Sarr[l] = S;
        }
    }
    __syncthreads();
    if (geo) {
        float e1l[CHUNK];
        #pragma unroll 4
        for (int l = 0; l < CHUNK; ++l) e1l[l] = __expf(A0 * Sarr[l]);
        #pragma unroll 2
        for (int l = 0; l < CHUNK; ++l) {
            float y = bf2f(yout[(size_t)(lbase + l) * 192 + d]);
            float e1 = e1l[l];
            float e = e1;
            float corr = 0.0f;
            #pragma unroll
            for (int n = 0; n < 16; ++n) {
                corr = fmaf(h0[n] * e, sC[l * 16 + n], corr);
                e *= e1;
            }
            yout[(size_t)(lbase + l) * 192 + d] = f2bf(y + corr);
        }
    } else {
        for (int l = 0; l < CHUNK; ++l) {
            float y = bf2f(yout[(size_t)(lbase + l) * 192 + d]);
            float corr = 0.0f;
            #pragma unroll
            for (int n = 0; n < 16; ++n) {
                float e = __expf(A[n] * Sarr[l]);
                corr = fmaf(h0[n] * e, sC[l * 16 + n], corr);
            }
            yout[(size_t)(lbase + l) * 192 + d] = f2bf(y + corr);
        }
    }
}

// merge + LayerNorm + gate (bf16 z) -> g (bf16, LDS) -> MFMA out GEMM. [proven]
__global__ __launch_bounds__(256) void k_lnout(
        const unsigned short* __restrict__ yout,
        const unsigned short* __restrict__ zb,
        const float* __restrict__ lng, const float* __restrict__ lnb,
        const unsigned short* __restrict__ Wo_bf, float* __restrict__ out) {
    __shared__ __align__(16) short sgb[32 * GSTRIDE];
    int p0 = blockIdx.x * 32;
    int t = threadIdx.x;
    int p = t >> 3;                    // pixel 0..31
    int sub = t & 7;                   // 8 threads per pixel, 24 channels each
    int gp = p0 + p;
    int b = gp >> 12;
    int hw = gp & 4095;
    int h = hw >> 6, w = hw & 63;
    int kq = (h & 1) ? ((w & 1) ? 3 : 1) : ((w & 1) ? 2 : 0);
    int l = (kq & 1) ? ((w >> 1) * 32 + (h >> 1))
                     : ((h >> 1) * 32 + (w >> 1));
    const unsigned short* yrow =
        yout + ((size_t)(b * 4 + kq) * 1024 + l) * 192 + sub * 24;
    float yv[24];
    float s = 0.0f, s2 = 0.0f;
    #pragma unroll
    for (int j = 0; j < 3; ++j) {
        ushort8v v8 = *(const ushort8v*)(yrow + j * 8);
        #pragma unroll
        for (int e = 0; e < 8; ++e) {
            float v = bf2f(v8[e]);
            yv[j * 8 + e] = v;
            s += v;
            s2 += v * v;
        }
    }
    #pragma unroll
    for (int off = 1; off < 8; off <<= 1) {
        s  += __shfl_xor(s, off, 8);
        s2 += __shfl_xor(s2, off, 8);
    }
    float mu = s * (1.0f / 192.0f);
    float var = s2 * (1.0f / 192.0f) - mu * mu;
    float rstd = rsqrtf(var + 1e-5f);
    const unsigned short* zrow = zb + (size_t)gp * 192 + sub * 24;
    short* grow = sgb + p * GSTRIDE + sub * 24;
    #pragma unroll
    for (int j = 0; j < 6; ++j) {
        ushort4v zv4 = *(const ushort4v*)(zrow + j * 4);
        float4 gv = *(const float4*)(lng + sub * 24 + j * 4);
        float4 bv = *(const float4*)(lnb + sub * 24 + j * 4);
        short4v sv;
        sv.x = (short)f2bf(((yv[j * 4 + 0] - mu) * rstd * gv.x + bv.x) * bf2f(zv4.x));
        sv.y = (short)f2bf(((yv[j * 4 + 1] - mu) * rstd * gv.y + bv.y) * bf2f(zv4.y));
        sv.z = (short)f2bf(((yv[j * 4 + 2] - mu) * rstd * gv.z + bv.z) * bf2f(zv4.z));
        sv.w = (short)f2bf(((yv[j * 4 + 3] - mu) * rstd * gv.w + bv.w) * bf2f(zv4.w));
        *(short4v*)(grow + j * 4) = sv;
    }
    __syncthreads();
    int wv = t >> 6;
    int lane = t & 63;
    int m = lane & 15, quad = lane >> 4;
    int mt = wv >> 1;
    int nb = (wv & 1) * 3;
    const short* wob = (const short*)Wo_bf;
    short8 a[6];
    #pragma unroll
    for (int kk = 0; kk < 6; ++kk)
        a[kk] = *(const short8*)(sgb + (mt * 16 + m) * GSTRIDE + kk * 32 + quad * 8);
    #pragma unroll
    for (int i = 0; i < 3; ++i) {
        int n0 = (nb + i) * 16;
        f32x4 acc = {0.f, 0.f, 0.f, 0.f};
        #pragma unroll
        for (int kk = 0; kk < 6; ++kk) {
            short8 bfr = *(const short8*)(wob + (size_t)(n0 + m) * 192 + kk * 32 + quad * 8);
            acc = __builtin_amdgcn_mfma_f32_16x16x32_bf16(a[kk], bfr, acc, 0, 0, 0);
        }
        #pragma unroll
        for (int r = 0; r < 4; ++r) {
            int pp = p0 + mt * 16 + quad * 4 + r;
            out[(size_t)pp * 96 + n0 + m] = acc[r];
        }
    }
}

extern "C" void kernel_launch(void* const* d_in, const int* in_sizes, int n_in,
                              void* d_out, int out_size, void* d_ws, size_t ws_size,
                              hipStream_t stream) {
    const float* x    = (const float*)d_in[0];
    const float* W_in = (const float*)d_in[1];
    const float* cw   = (const float*)d_in[2];
    const float* cb   = (const float*)d_in[3];
    const float* xpw  = (const float*)d_in[4];
    const float* dtw  = (const float*)d_in[5];
    const float* dtb  = (const float*)d_in[6];
    const float* Alog = (const float*)d_in[7];
    const float* Ds   = (const float*)d_in[8];
    const float* lng  = (const float*)d_in[9];
    const float* lnb  = (const float*)d_in[10];
    const float* Wout = (const float*)d_in[11];
    float* out = (float*)d_out;

    float* ws = (float*)d_ws;
    size_t off = 0;
    unsigned short* Wi_hi = (unsigned short*)(ws + off); off += 384 * 96 / 2;
    unsigned short* Wi_lo = (unsigned short*)(ws + off); off += 384 * 96 / 2;
    unsigned short* Xp_hi = (unsigned short*)(ws + off); off += 4 * 48 * 192 / 2;
    unsigned short* Xp_lo = (unsigned short*)(ws + off); off += 4 * 48 * 192 / 2;
    unsigned short* Wo_bf = (unsigned short*)(ws + off); off += 96 * DINNER / 2;
    float* xin   = ws + off; off += (size_t)NPIX * 192;
    unsigned short* zb = (unsigned short*)(ws + off); off += (size_t)NPIX * 192 / 2;
    float* xg    = ws + off; off += (size_t)NPIX * 192;
    float* dtrb  = ws + off; off += (size_t)NBK * LP * 6;
    float* Cm    = ws + off; off += (size_t)NBK * LP * 16;
    float* Sbuf  = ws + off; off += (size_t)NCH * SSTRIDE;
    unsigned short* Qb  = (unsigned short*)(ws + off); off += (size_t)NCH * NSTATES / 2;
    unsigned short* yout = (unsigned short*)(ws + off); off += (size_t)NBK * LP * 192 / 2;

    hipLaunchKernelGGL(k_castW, dim3(144), dim3(256), 0, stream,
                       W_in, xpw, Wout, Wi_hi, Wi_lo, Xp_hi, Xp_lo, Wo_bf);
    hipLaunchKernelGGL(k_inproj3, dim3(NPIX / 16), dim3(256), 0, stream,
                       x, Wi_hi, Wi_lo, xin, zb);
    hipLaunchKernelGGL(k_conv8, dim3(NPIX / 8), dim3(192), 0, stream,
                       xin, cw, cb, xg);
    hipLaunchKernelGGL(k_xscan, dim3(NBK * NCH), dim3(192), 0, stream,
                       xg, Xp_hi, Xp_lo, Alog, dtw, dtb, Ds,
                       dtrb, Cm, Sbuf, Qb, yout);
    hipLaunchKernelGGL(k_scan3p, dim3(NBK * NCH), dim3(192), 0, stream,
                       dtrb, Cm, Alog, dtw, dtb, Sbuf, Qb, yout);
    hipLaunchKernelGGL(k_lnout, dim3(NPIX / 32), dim3(256), 0, stream,
                       yout, zb, lng, lnb, Wo_bf, out);
}

// Round 9
// 165.894 us; speedup vs baseline: 1.0033x; 1.0033x over previous
//
#include <hip/hip_runtime.h>
#include <math.h>

// SS2D (VMamba v2) forward — MI355X gfx950.
// 6 dispatches. R9 = R7 config + ONE change: k_scan3p block remap to
// longest-job-first (bid -> ch=63-bid>>4, bk=bid&15) so the 16 most
// expensive prefix blocks (ch=63) launch first instead of last.
// Bit-exact per-block work; pure scheduling change.
//  k_castW   : W_in -> (hi,lo); xpw -> (hi,lo, 48-row padded); W_out -> bf16
//  k_inproj3 : xz = x @ W_in^T via bf16x3 MFMA (16-px tiles)   [proven]
//  k_conv8   : depthwise 3x3 + bias + silu -> xg               [proven]
//  k_xscan   : fused x_dbl MFMA + local scan -> yout/Qb/Sbuf + dtr/Cm [proven R5]
//  k_scan3p  : correction with chunk-prefix folded in; LJF block order [R9]
//  k_lnout   : merge + LayerNorm + gate -> MFMA out GEMM       [proven]

#define DINNER 192
#define NSTATE 16
#define KDIR 4
#define BATCH 4
#define NPIX (BATCH * 64 * 64)          // 16384
#define LP 1024
#define NCH 64                          // scan chunks
#define CHUNK 16                        // LP / NCH
#define NBK (BATCH * KDIR)              // 16
#define NSTATES (NBK * DINNER * NSTATE) // 49152
#define SSTRIDE (NBK * DINNER)          // 3072 floats of S per chunk
#define USTRIDE 196                     // scan sU row stride (floats)
#define GSTRIDE 200                     // lnout bf16 g LDS stride (shorts)
#define ASTRIDE 104                     // inproj LDS A stride (shorts, 96 padded)
#define XSTRIDE 200                     // xdbl LDS A stride (shorts, 192 padded)

typedef __attribute__((ext_vector_type(8))) short short8;
typedef __attribute__((ext_vector_type(4))) short short4v;
typedef __attribute__((ext_vector_type(4))) unsigned short ushort4v;
typedef __attribute__((ext_vector_type(8))) unsigned short ushort8v;
typedef __attribute__((ext_vector_type(4))) float f32x4;

__device__ __forceinline__ float silu_f(float x) {
    return x / (1.0f + __expf(-x));
}
__device__ __forceinline__ float softplus_f(float a) {
    return (a > 20.0f) ? a : __logf(1.0f + __expf(a));
}
__device__ __forceinline__ unsigned short f2bf(float f) {
    unsigned u = __float_as_uint(f);
    unsigned r = (u + 0x7FFFu + ((u >> 16) & 1u)) >> 16;
    return (unsigned short)r;
}
__device__ __forceinline__ float bf2f(unsigned short h) {
    return __uint_as_float(((unsigned)h) << 16);
}

// Weights: W_in hi/lo split; xpw hi/lo split into 48-row padded layout
// (rows 38..47 zero); W_out bf16 cast.
__global__ __launch_bounds__(256) void k_castW(
        const float* __restrict__ W_in, const float* __restrict__ xpw,
        const float* __restrict__ W_out,
        unsigned short* __restrict__ Wi_hi, unsigned short* __restrict__ Wi_lo,
        unsigned short* __restrict__ Xp_hi, unsigned short* __restrict__ Xp_lo,
        unsigned short* __restrict__ Wo_bf) {
    int i = blockIdx.x * 256 + threadIdx.x;
    if (i < 384 * 96) {
        float v = W_in[i];
        unsigned short h = f2bf(v);
        Wi_hi[i] = h;
        Wi_lo[i] = f2bf(v - bf2f(h));
    }
    if (i < 4 * 48 * 192) {           // padded xpw split
        int kk = i / (48 * 192);
        int rem = i - kk * (48 * 192);
        int c = rem / 192;
        int j = rem - c * 192;
        float v = (c < 38) ? xpw[((size_t)kk * 38 + c) * 192 + j] : 0.0f;
        unsigned short h = f2bf(v);
        Xp_hi[i] = h;
        Xp_lo[i] = f2bf(v - bf2f(h));
    }
    if (i < 96 * DINNER) Wo_bf[i] = f2bf(W_out[i]);
}

// MFMA in-proj (bf16x3 split); x split staged ONCE in LDS (shared by 4 waves).
__global__ __launch_bounds__(256) void k_inproj3(
        const float* __restrict__ x,
        const unsigned short* __restrict__ Wi_hi,
        const unsigned short* __restrict__ Wi_lo,
        float* __restrict__ xin, unsigned short* __restrict__ zb) {
    __shared__ __align__(16) short sAh[16 * ASTRIDE];
    __shared__ __align__(16) short sAl[16 * ASTRIDE];
    int p0 = blockIdx.x * 16;
    int t = threadIdx.x;
    const float4* xs = (const float4*)(x + (size_t)p0 * 96);
    for (int i = t; i < 384; i += 256) {     // 16*96 floats = 384 float4
        float4 v = xs[i];
        int f = i * 4;
        int row = f / 96, col = f - row * 96;
        short4v hi, lo;
        unsigned short hb;
        hb = f2bf(v.x); hi.x = (short)hb; lo.x = (short)f2bf(v.x - bf2f(hb));
        hb = f2bf(v.y); hi.y = (short)hb; lo.y = (short)f2bf(v.y - bf2f(hb));
        hb = f2bf(v.z); hi.z = (short)hb; lo.z = (short)f2bf(v.z - bf2f(hb));
        hb = f2bf(v.w); hi.w = (short)hb; lo.w = (short)f2bf(v.w - bf2f(hb));
        *(short4v*)&sAh[row * ASTRIDE + col] = hi;
        *(short4v*)&sAl[row * ASTRIDE + col] = lo;
    }
    __syncthreads();
    int w = t >> 6;
    int lane = t & 63;
    int m = lane & 15, quad = lane >> 4;
    const short* wh = (const short*)Wi_hi;
    const short* wl = (const short*)Wi_lo;
    short8 ah[3], al[3];
    #pragma unroll
    for (int c = 0; c < 3; ++c) {
        ah[c] = *(const short8*)&sAh[m * ASTRIDE + c * 32 + quad * 8];
        al[c] = *(const short8*)&sAl[m * ASTRIDE + c * 32 + quad * 8];
    }
    #pragma unroll
    for (int i = 0; i < 6; ++i) {
        int e0 = (w * 6 + i) * 16;
        f32x4 acc = {0.f, 0.f, 0.f, 0.f};
        #pragma unroll
        for (int c = 0; c < 3; ++c) {
            size_t o = (size_t)(e0 + m) * 96 + c * 32 + quad * 8;
            short8 bh = *(const short8*)(wh + o);
            short8 bl = *(const short8*)(wl + o);
            acc = __builtin_amdgcn_mfma_f32_16x16x32_bf16(ah[c], bl, acc, 0, 0, 0);
            acc = __builtin_amdgcn_mfma_f32_16x16x32_bf16(al[c], bh, acc, 0, 0, 0);
            acc = __builtin_amdgcn_mfma_f32_16x16x32_bf16(ah[c], bh, acc, 0, 0, 0);
        }
        int e = e0 + m;
        #pragma unroll
        for (int r = 0; r < 4; ++r) {
            int p = p0 + quad * 4 + r;
            if (e < 192) xin[(size_t)p * 192 + e] = acc[r];
            else         zb[(size_t)p * 192 + (e - 192)] = f2bf(silu_f(acc[r]));
        }
    }
}

// depthwise 3x3, 8 pixels/block; full 3x10 window preloaded into registers.
__global__ __launch_bounds__(192) void k_conv8(
        const float* __restrict__ xin, const float* __restrict__ cw,
        const float* __restrict__ cb, float* __restrict__ xg) {
    int blk = blockIdx.x;             // 2048 = 4 b * 64 h * 8 wchunks
    int b = blk >> 9;
    int rem = blk & 511;
    int h = rem >> 3;
    int w0 = (rem & 7) * 8;
    int d = threadIdx.x;
    float wr[3][3];
    #pragma unroll
    for (int i = 0; i < 3; ++i)
        #pragma unroll
        for (int j = 0; j < 3; ++j) wr[i][j] = cw[d * 9 + i * 3 + j];
    float bias = cb[d];
    float r0[10], r1[10], r2[10];
    #pragma unroll
    for (int jj = 0; jj < 10; ++jj) {
        int ww = w0 + jj - 1;
        bool inw = (unsigned)ww < 64u;        // block-uniform
        const float* base = xin + ((size_t)b * 4096 + h * 64 + (inw ? ww : 0)) * 192 + d;
        r0[jj] = (inw && h > 0)  ? base[-64 * 192] : 0.0f;
        r1[jj] = inw             ? base[0]         : 0.0f;
        r2[jj] = (inw && h < 63) ? base[64 * 192]  : 0.0f;
    }
    float acc[8];
    #pragma unroll
    for (int o = 0; o < 8; ++o) {
        float a = bias;
        #pragma unroll
        for (int j = 0; j < 3; ++j) {
            a = fmaf(r0[o + j], wr[0][j], a);
            a = fmaf(r1[o + j], wr[1][j], a);
            a = fmaf(r2[o + j], wr[2][j], a);
        }
        acc[o] = a;
    }
    #pragma unroll
    for (int o = 0; o < 8; ++o) {
        int w = w0 + o;
        int kq = (h & 1) ? ((w & 1) ? 3 : 1) : ((w & 1) ? 2 : 0);
        int l = (kq & 1) ? ((w >> 1) * 32 + (h >> 1))
                         : ((h >> 1) * 32 + (w >> 1));
        xg[((size_t)(b * 4 + kq) * 1024 + l) * 192 + d] = silu_f(acc[o]);
    }
}

// Fused x_dbl MFMA + local scan (h_in = 0). [proven R5]
__global__ __launch_bounds__(192) void k_xscan(
        const float* __restrict__ xg,
        const unsigned short* __restrict__ Xp_hi,
        const unsigned short* __restrict__ Xp_lo,
        const float* __restrict__ A_logs, const float* __restrict__ dtw,
        const float* __restrict__ dtb, const float* __restrict__ Ds,
        float* __restrict__ dtr, float* __restrict__ Cm,
        float* __restrict__ Sbuf, unsigned short* __restrict__ Qb,
        unsigned short* __restrict__ yout) {
    __shared__ __align__(16) short sAh[16 * XSTRIDE];
    __shared__ __align__(16) short sAl[16 * XSTRIDE];
    __shared__ __align__(16) float sU[CHUNK * USTRIDE];
    __shared__ float sB[CHUNK * 16];
    __shared__ float sC[CHUNK * 16];
    __shared__ float sDt[CHUNK * 6];

    int bk = blockIdx.x >> 6;
    int ch = blockIdx.x & 63;
    int k = bk & 3;
    int t = threadIdx.x;
    int d = t;
    int lbase = bk * 1024 + ch * CHUNK;

    // ---- stage u tile: fp32 sU + bf16 hi/lo split ----
    {
        const float4* us = (const float4*)(xg + (size_t)lbase * 192);
        for (int i = t; i < 768; i += 192) {     // 16*192 floats = 768 float4
            float4 v = us[i];
            int f = i * 4;
            int row = f / 192, col = f - row * 192;
            short4v hi, lo;
            unsigned short hb;
            hb = f2bf(v.x); hi.x = (short)hb; lo.x = (short)f2bf(v.x - bf2f(hb));
            hb = f2bf(v.y); hi.y = (short)hb; lo.y = (short)f2bf(v.y - bf2f(hb));
            hb = f2bf(v.z); hi.z = (short)hb; lo.z = (short)f2bf(v.z - bf2f(hb));
            hb = f2bf(v.w); hi.w = (short)hb; lo.w = (short)f2bf(v.w - bf2f(hb));
            *(short4v*)&sAh[row * XSTRIDE + col] = hi;
            *(short4v*)&sAl[row * XSTRIDE + col] = lo;
            *(float4*)&sU[row * USTRIDE + col] = v;
        }
    }
    __syncthreads();

    // ---- x_dbl MFMA (k_xdbl body), stores -> sDt/sB/sC ----
    {
        int wv = t >> 6;                  // N-tile 0..2
        int lane = t & 63;
        int m = lane & 15, quad = lane >> 4;
        const short* bh16 = (const short*)Xp_hi;
        const short* bl16 = (const short*)Xp_lo;
        int n0 = wv * 16;
        size_t brow = ((size_t)k * 48 + n0 + m) * 192;
        f32x4 acc = {0.f, 0.f, 0.f, 0.f};
        #pragma unroll
        for (int c = 0; c < 6; ++c) {
            short8 ah = *(const short8*)&sAh[m * XSTRIDE + c * 32 + quad * 8];
            short8 al = *(const short8*)&sAl[m * XSTRIDE + c * 32 + quad * 8];
            short8 bh = *(const short8*)(bh16 + brow + c * 32 + quad * 8);
            short8 bl = *(const short8*)(bl16 + brow + c * 32 + quad * 8);
            acc = __builtin_amdgcn_mfma_f32_16x16x32_bf16(ah, bl, acc, 0, 0, 0);
            acc = __builtin_amdgcn_mfma_f32_16x16x32_bf16(al, bh, acc, 0, 0, 0);
            acc = __builtin_amdgcn_mfma_f32_16x16x32_bf16(ah, bh, acc, 0, 0, 0);
        }
        int c = n0 + m;                   // output c-row
        #pragma unroll
        for (int r = 0; r < 4; ++r) {
            int ll = quad * 4 + r;
            float v = acc[r];
            if (c < 6)       sDt[ll * 6 + c] = v;
            else if (c < 22) sB[ll * 16 + (c - 6)] = v;
            else if (c < 38) sC[ll * 16 + (c - 22)] = v;
        }
    }
    __syncthreads();

    // ---- dump dtr / Cm for k_scan3p ----
    if (t < 96) dtr[(size_t)(lbase + t / 6) * 6 + (t % 6)] = sDt[t];
    for (int i = t; i < CHUNK * 16; i += 192)
        Cm[(size_t)lbase * 16 + i] = sC[i];

    // ---- local scan (k_scan1y body; dlt from sDt, u from fp32 sU) ----
    {
        float A[16];
        #pragma unroll
        for (int n = 0; n < 16; ++n) A[n] = -__expf(A_logs[(k * 192 + d) * 16 + n]);
        float A0 = A[0];
        bool geo = true;                 // A[n] == (n+1)*A[0] (geometric ladder)?
        #pragma unroll
        for (int n = 1; n < 16; ++n)
            geo = geo && (fabsf(A[n] - (float)(n + 1) * A0) <= 1e-4f * fabsf(A[n]));
        float wp[6];
        #pragma unroll
        for (int q = 0; q < 6; ++q) wp[q] = dtw[(k * 192 + d) * 6 + q];
        float bias = dtb[k * 192 + d];
        float Dp = Ds[k * 192 + d];
        float dlt[CHUNK];
        #pragma unroll 4
        for (int l = 0; l < CHUNK; ++l) {
            float a = bias;
            #pragma unroll
            for (int q = 0; q < 6; ++q) a = fmaf(wp[q], sDt[l * 6 + q], a);
            dlt[l] = softplus_f(a);
        }
        float S = 0.0f;
        #pragma unroll
        for (int l = 0; l < CHUNK; ++l) S += dlt[l];
        float h[16];
        #pragma unroll
        for (int n = 0; n < 16; ++n) h[n] = 0.0f;
        if (geo) {
            float e1v[CHUNK];
            #pragma unroll 4
            for (int l = 0; l < CHUNK; ++l) e1v[l] = __expf(dlt[l] * A0);
            #pragma unroll 2
            for (int l = 0; l < CHUNK; ++l) {
                float u = sU[l * USTRIDE + d];
                float du = dlt[l] * u;
                float e1 = e1v[l];
                float e = e1;
                float y = 0.0f;
                #pragma unroll
                for (int n = 0; n < 16; ++n) {
                    h[n] = fmaf(e, h[n], du * sB[l * 16 + n]);
                    y = fmaf(h[n], sC[l * 16 + n], y);
                    e *= e1;
                }
                yout[(size_t)(lbase + l) * 192 + d] = f2bf(fmaf(u, Dp, y));
            }
        } else {
            for (int l = 0; l < CHUNK; ++l) {
                float u = sU[l * USTRIDE + d];
                float du = dlt[l] * u;
                float y = 0.0f;
                #pragma unroll
                for (int n = 0; n < 16; ++n) {
                    float e = __expf(dlt[l] * A[n]);
                    h[n] = fmaf(e, h[n], du * sB[l * 16 + n]);
                    y = fmaf(h[n], sC[l * 16 + n], y);
                }
                yout[(size_t)(lbase + l) * 192 + d] = f2bf(fmaf(u, Dp, y));
            }
        }
        Sbuf[(size_t)ch * SSTRIDE + bk * 192 + d] = S;
        size_t base = (size_t)ch * NSTATES + bk * (192 * 16);
        #pragma unroll
        for (int n = 0; n < 16; ++n)
            Qb[base + n * 192 + d] = f2bf(h[n]);
    }
}

// Chain-free correction with the chunk-prefix folded in (replaces k_scan2).
// R9: longest-job-first block order — bid -> (ch = 63-bid>>4, bk = bid&15),
// so the 16 ch=63 blocks (longest prefix) start first. Bit-exact remap.
__global__ __launch_bounds__(192) void k_scan3p(
        const float* __restrict__ dtr, const float* __restrict__ Cm,
        const float* __restrict__ A_logs, const float* __restrict__ dtw,
        const float* __restrict__ dtb,
        const float* __restrict__ Sbuf, const unsigned short* __restrict__ Qb,
        unsigned short* __restrict__ yout) {
    __shared__ float sC[CHUNK * 16];
    int bk = blockIdx.x & 15;
    int ch = 63 - (blockIdx.x >> 4);
    if (ch == 0) return;              // h0 == 0, no correction
    int k = bk & 3;
    int d = threadIdx.x;
    int lbase = bk * 1024 + ch * CHUNK;
    for (int i = d; i < CHUNK * 16; i += 192)
        sC[i] = Cm[(size_t)lbase * 16 + i];
    float A[16];
    #pragma unroll
    for (int n = 0; n < 16; ++n) A[n] = -__expf(A_logs[(k * 192 + d) * 16 + n]);
    float A0 = A[0];
    bool geo = true;
    #pragma unroll
    for (int n = 1; n < 16; ++n)
        geo = geo && (fabsf(A[n] - (float)(n + 1) * A0) <= 1e-4f * fabsf(A[n]));
    float wp[6];
    #pragma unroll
    for (int q = 0; q < 6; ++q) wp[q] = dtw[(k * 192 + d) * 6 + q];
    float bias = dtb[k * 192 + d];

    // ---- h0 prefix over chunks 0..ch-1 (was k_scan2 + Hst) ----
    float h0[16];
    #pragma unroll
    for (int n = 0; n < 16; ++n) h0[n] = 0.0f;
    {
        int sb = bk * 192 + d;
        size_t qoff = (size_t)bk * 3072 + d;
        if (geo) {
            for (int c = 0; c < ch; ++c) {
                float Sv = Sbuf[(size_t)c * SSTRIDE + sb];
                float e1 = __expf(A0 * Sv);
                float e = e1;
                const unsigned short* qrow = Qb + (size_t)c * NSTATES + qoff;
                #pragma unroll
                for (int n = 0; n < 16; ++n) {
                    h0[n] = fmaf(e, h0[n], bf2f(qrow[n * 192]));
                    e *= e1;
                }
            }
        } else {
            for (int c = 0; c < ch; ++c) {
                float Sv = Sbuf[(size_t)c * SSTRIDE + sb];
                const unsigned short* qrow = Qb + (size_t)c * NSTATES + qoff;
                #pragma unroll
                for (int n = 0; n < 16; ++n)
                    h0[n] = fmaf(__expf(A[n] * Sv), h0[n], bf2f(qrow[n * 192]));
            }
        }
    }

    float Sarr[CHUNK];
    {
        float S = 0.0f;
        #pragma unroll 4
        for (int l = 0; l < CHUNK; ++l) {
            const float* r = dtr + (size_t)(lbase + l) * 6;   // wave-uniform
            float a = bias;
            #pragma unroll
            for (int q = 0; q < 6; ++q) a = fmaf(wp[q], r[q], a);
            S += softplus_f(a);
            Sarr[l] = S;
        }
    }
    __syncthreads();
    if (geo) {
        float e1l[CHUNK];
        #pragma unroll 4
        for (int l = 0; l < CHUNK; ++l) e1l[l] = __expf(A0 * Sarr[l]);
        #pragma unroll 2
        for (int l = 0; l < CHUNK; ++l) {
            float y = bf2f(yout[(size_t)(lbase + l) * 192 + d]);
            float e1 = e1l[l];
            float e = e1;
            float corr = 0.0f;
            #pragma unroll
            for (int n = 0; n < 16; ++n) {
                corr = fmaf(h0[n] * e, sC[l * 16 + n], corr);
                e *= e1;
            }
            yout[(size_t)(lbase + l) * 192 + d] = f2bf(y + corr);
        }
    } else {
        for (int l = 0; l < CHUNK; ++l) {
            float y = bf2f(yout[(size_t)(lbase + l) * 192 + d]);
            float corr = 0.0f;
            #pragma unroll
            for (int n = 0; n < 16; ++n) {
                float e = __expf(A[n] * Sarr[l]);
                corr = fmaf(h0[n] * e, sC[l * 16 + n], corr);
            }
            yout[(size_t)(lbase + l) * 192 + d] = f2bf(y + corr);
        }
    }
}

// merge + LayerNorm + gate (bf16 z) -> g (bf16, LDS) -> MFMA out GEMM. [proven]
__global__ __launch_bounds__(256) void k_lnout(
        const unsigned short* __restrict__ yout,
        const unsigned short* __restrict__ zb,
        const float* __restrict__ lng, const float* __restrict__ lnb,
        const unsigned short* __restrict__ Wo_bf, float* __restrict__ out) {
    __shared__ __align__(16) short sgb[32 * GSTRIDE];
    int p0 = blockIdx.x * 32;
    int t = threadIdx.x;
    int p = t >> 3;                    // pixel 0..31
    int sub = t & 7;                   // 8 threads per pixel, 24 channels each
    int gp = p0 + p;
    int b = gp >> 12;
    int hw = gp & 4095;
    int h = hw >> 6, w = hw & 63;
    int kq = (h & 1) ? ((w & 1) ? 3 : 1) : ((w & 1) ? 2 : 0);
    int l = (kq & 1) ? ((w >> 1) * 32 + (h >> 1))
                     : ((h >> 1) * 32 + (w >> 1));
    const unsigned short* yrow =
        yout + ((size_t)(b * 4 + kq) * 1024 + l) * 192 + sub * 24;
    float yv[24];
    float s = 0.0f, s2 = 0.0f;
    #pragma unroll
    for (int j = 0; j < 3; ++j) {
        ushort8v v8 = *(const ushort8v*)(yrow + j * 8);
        #pragma unroll
        for (int e = 0; e < 8; ++e) {
            float v = bf2f(v8[e]);
            yv[j * 8 + e] = v;
            s += v;
            s2 += v * v;
        }
    }
    #pragma unroll
    for (int off = 1; off < 8; off <<= 1) {
        s  += __shfl_xor(s, off, 8);
        s2 += __shfl_xor(s2, off, 8);
    }
    float mu = s * (1.0f / 192.0f);
    float var = s2 * (1.0f / 192.0f) - mu * mu;
    float rstd = rsqrtf(var + 1e-5f);
    const unsigned short* zrow = zb + (size_t)gp * 192 + sub * 24;
    short* grow = sgb + p * GSTRIDE + sub * 24;
    #pragma unroll
    for (int j = 0; j < 6; ++j) {
        ushort4v zv4 = *(const ushort4v*)(zrow + j * 4);
        float4 gv = *(const float4*)(lng + sub * 24 + j * 4);
        float4 bv = *(const float4*)(lnb + sub * 24 + j * 4);
        short4v sv;
        sv.x = (short)f2bf(((yv[j * 4 + 0] - mu) * rstd * gv.x + bv.x) * bf2f(zv4.x));
        sv.y = (short)f2bf(((yv[j * 4 + 1] - mu) * rstd * gv.y + bv.y) * bf2f(zv4.y));
        sv.z = (short)f2bf(((yv[j * 4 + 2] - mu) * rstd * gv.z + bv.z) * bf2f(zv4.z));
        sv.w = (short)f2bf(((yv[j * 4 + 3] - mu) * rstd * gv.w + bv.w) * bf2f(zv4.w));
        *(short4v*)(grow + j * 4) = sv;
    }
    __syncthreads();
    int wv = t >> 6;
    int lane = t & 63;
    int m = lane & 15, quad = lane >> 4;
    int mt = wv >> 1;
    int nb = (wv & 1) * 3;
    const short* wob = (const short*)Wo_bf;
    short8 a[6];
    #pragma unroll
    for (int kk = 0; kk < 6; ++kk)
        a[kk] = *(const short8*)(sgb + (mt * 16 + m) * GSTRIDE + kk * 32 + quad * 8);
    #pragma unroll
    for (int i = 0; i < 3; ++i) {
        int n0 = (nb + i) * 16;
        f32x4 acc = {0.f, 0.f, 0.f, 0.f};
        #pragma unroll
        for (int kk = 0; kk < 6; ++kk) {
            short8 bfr = *(const short8*)(wob + (size_t)(n0 + m) * 192 + kk * 32 + quad * 8);
            acc = __builtin_amdgcn_mfma_f32_16x16x32_bf16(a[kk], bfr, acc, 0, 0, 0);
        }
        #pragma unroll
        for (int r = 0; r < 4; ++r) {
            int pp = p0 + mt * 16 + quad * 4 + r;
            out[(size_t)pp * 96 + n0 + m] = acc[r];
        }
    }
}

extern "C" void kernel_launch(void* const* d_in, const int* in_sizes, int n_in,
                              void* d_out, int out_size, void* d_ws, size_t ws_size,
                              hipStream_t stream) {
    const float* x    = (const float*)d_in[0];
    const float* W_in = (const float*)d_in[1];
    const float* cw   = (const float*)d_in[2];
    const float* cb   = (const float*)d_in[3];
    const float* xpw  = (const float*)d_in[4];
    const float* dtw  = (const float*)d_in[5];
    const float* dtb  = (const float*)d_in[6];
    const float* Alog = (const float*)d_in[7];
    const float* Ds   = (const float*)d_in[8];
    const float* lng  = (const float*)d_in[9];
    const float* lnb  = (const float*)d_in[10];
    const float* Wout = (const float*)d_in[11];
    float* out = (float*)d_out;

    float* ws = (float*)d_ws;
    size_t off = 0;
    unsigned short* Wi_hi = (unsigned short*)(ws + off); off += 384 * 96 / 2;
    unsigned short* Wi_lo = (unsigned short*)(ws + off); off += 384 * 96 / 2;
    unsigned short* Xp_hi = (unsigned short*)(ws + off); off += 4 * 48 * 192 / 2;
    unsigned short* Xp_lo = (unsigned short*)(ws + off); off += 4 * 48 * 192 / 2;
    unsigned short* Wo_bf = (unsigned short*)(ws + off); off += 96 * DINNER / 2;
    float* xin   = ws + off; off += (size_t)NPIX * 192;
    unsigned short* zb = (unsigned short*)(ws + off); off += (size_t)NPIX * 192 / 2;
    float* xg    = ws + off; off += (size_t)NPIX * 192;
    float* dtrb  = ws + off; off += (size_t)NBK * LP * 6;
    float* Cm    = ws + off; off += (size_t)NBK * LP * 16;
    float* Sbuf  = ws + off; off += (size_t)NCH * SSTRIDE;
    unsigned short* Qb  = (unsigned short*)(ws + off); off += (size_t)NCH * NSTATES / 2;
    unsigned short* yout = (unsigned short*)(ws + off); off += (size_t)NBK * LP * 192 / 2;

    hipLaunchKernelGGL(k_castW, dim3(144), dim3(256), 0, stream,
                       W_in, xpw, Wout, Wi_hi, Wi_lo, Xp_hi, Xp_lo, Wo_bf);
    hipLaunchKernelGGL(k_inproj3, dim3(NPIX / 16), dim3(256), 0, stream,
                       x, Wi_hi, Wi_lo, xin, zb);
    hipLaunchKernelGGL(k_conv8, dim3(NPIX / 8), dim3(192), 0, stream,
                       xin, cw, cb, xg);
    hipLaunchKernelGGL(k_xscan, dim3(NBK * NCH), dim3(192), 0, stream,
                       xg, Xp_hi, Xp_lo, Alog, dtw, dtb, Ds,
                       dtrb, Cm, Sbuf, Qb, yout);
    hipLaunchKernelGGL(k_scan3p, dim3(NBK * NCH), dim3(192), 0, stream,
                       dtrb, Cm, Alog, dtw, dtb, Sbuf, Qb, yout);
    hipLaunchKernelGGL(k_lnout, dim3(NPIX / 32), dim3(256), 0, stream,
                       yout, zb, lng, lnb, Wo_bf, out);
}

// Round 10
// 155.287 us; speedup vs baseline: 1.0718x; 1.0683x over previous
//
#include <hip/hip_runtime.h>
#include <math.h>

// SS2D (VMamba v2) forward — MI355X gfx950.
// R10 = exact revert to the R5-verified best config (156.2 us):
// 7 dispatches. Front-half fusion (k_xdbl+k_scan1y -> k_xscan, fp32 sU,
// bit-identical scan inputs); back half = round-0-proven k_scan2/k_scan3c/
// k_lnout. scan3p (folded prefix) refuted across R7/R8/R9: the ch=63
// block's 63-iter serial 16-deep FMA chain costs ~10us regardless of
// block order; k_scan2 distributes the same recurrence over 49152 threads.
//  k_castW   : W_in -> (hi,lo); xpw -> (hi,lo, 48-row padded); W_out -> bf16
//  k_inproj3 : xz = x @ W_in^T via bf16x3 MFMA
//  k_conv8   : depthwise 3x3 + bias + silu -> xg (quadrant layout)
//  k_xscan   : fused x_dbl MFMA + local scan -> yout/Qb/Sbuf + dtr/Cm dump
//  k_scan2   : prefix over 64 chunks (8x-batched); Hst bf16   [proven]
//  k_scan3c  : chain-free correction on bf16 yout              [proven]
//  k_lnout   : merge + LayerNorm + gate -> MFMA out GEMM       [proven]

#define DINNER 192
#define NSTATE 16
#define KDIR 4
#define BATCH 4
#define NPIX (BATCH * 64 * 64)          // 16384
#define LP 1024
#define NCH 64                          // scan chunks
#define CHUNK 16                        // LP / NCH
#define NBK (BATCH * KDIR)              // 16
#define NSTATES (NBK * DINNER * NSTATE) // 49152
#define SSTRIDE (NBK * DINNER)          // 3072 floats of S per chunk
#define USTRIDE 196                     // scan sU row stride (floats)
#define GSTRIDE 200                     // lnout bf16 g LDS stride (shorts)
#define ASTRIDE 104                     // inproj LDS A stride (shorts, 96 padded)
#define XSTRIDE 200                     // xdbl LDS A stride (shorts, 192 padded)

typedef __attribute__((ext_vector_type(8))) short short8;
typedef __attribute__((ext_vector_type(4))) short short4v;
typedef __attribute__((ext_vector_type(4))) unsigned short ushort4v;
typedef __attribute__((ext_vector_type(8))) unsigned short ushort8v;
typedef __attribute__((ext_vector_type(4))) float f32x4;

__device__ __forceinline__ float silu_f(float x) {
    return x / (1.0f + __expf(-x));
}
__device__ __forceinline__ float softplus_f(float a) {
    return (a > 20.0f) ? a : __logf(1.0f + __expf(a));
}
__device__ __forceinline__ unsigned short f2bf(float f) {
    unsigned u = __float_as_uint(f);
    unsigned r = (u + 0x7FFFu + ((u >> 16) & 1u)) >> 16;
    return (unsigned short)r;
}
__device__ __forceinline__ float bf2f(unsigned short h) {
    return __uint_as_float(((unsigned)h) << 16);
}

// Weights: W_in hi/lo split; xpw hi/lo split into 48-row padded layout
// (rows 38..47 zero); W_out bf16 cast.
__global__ __launch_bounds__(256) void k_castW(
        const float* __restrict__ W_in, const float* __restrict__ xpw,
        const float* __restrict__ W_out,
        unsigned short* __restrict__ Wi_hi, unsigned short* __restrict__ Wi_lo,
        unsigned short* __restrict__ Xp_hi, unsigned short* __restrict__ Xp_lo,
        unsigned short* __restrict__ Wo_bf) {
    int i = blockIdx.x * 256 + threadIdx.x;
    if (i < 384 * 96) {
        float v = W_in[i];
        unsigned short h = f2bf(v);
        Wi_hi[i] = h;
        Wi_lo[i] = f2bf(v - bf2f(h));
    }
    if (i < 4 * 48 * 192) {           // padded xpw split
        int kk = i / (48 * 192);
        int rem = i - kk * (48 * 192);
        int c = rem / 192;
        int j = rem - c * 192;
        float v = (c < 38) ? xpw[((size_t)kk * 38 + c) * 192 + j] : 0.0f;
        unsigned short h = f2bf(v);
        Xp_hi[i] = h;
        Xp_lo[i] = f2bf(v - bf2f(h));
    }
    if (i < 96 * DINNER) Wo_bf[i] = f2bf(W_out[i]);
}

// MFMA in-proj (bf16x3 split); x split staged ONCE in LDS (shared by 4 waves).
__global__ __launch_bounds__(256) void k_inproj3(
        const float* __restrict__ x,
        const unsigned short* __restrict__ Wi_hi,
        const unsigned short* __restrict__ Wi_lo,
        float* __restrict__ xin, unsigned short* __restrict__ zb) {
    __shared__ __align__(16) short sAh[16 * ASTRIDE];
    __shared__ __align__(16) short sAl[16 * ASTRIDE];
    int p0 = blockIdx.x * 16;
    int t = threadIdx.x;
    const float4* xs = (const float4*)(x + (size_t)p0 * 96);
    for (int i = t; i < 384; i += 256) {     // 16*96 floats = 384 float4
        float4 v = xs[i];
        int f = i * 4;
        int row = f / 96, col = f - row * 96;
        short4v hi, lo;
        unsigned short hb;
        hb = f2bf(v.x); hi.x = (short)hb; lo.x = (short)f2bf(v.x - bf2f(hb));
        hb = f2bf(v.y); hi.y = (short)hb; lo.y = (short)f2bf(v.y - bf2f(hb));
        hb = f2bf(v.z); hi.z = (short)hb; lo.z = (short)f2bf(v.z - bf2f(hb));
        hb = f2bf(v.w); hi.w = (short)hb; lo.w = (short)f2bf(v.w - bf2f(hb));
        *(short4v*)&sAh[row * ASTRIDE + col] = hi;
        *(short4v*)&sAl[row * ASTRIDE + col] = lo;
    }
    __syncthreads();
    int w = t >> 6;
    int lane = t & 63;
    int m = lane & 15, quad = lane >> 4;
    const short* wh = (const short*)Wi_hi;
    const short* wl = (const short*)Wi_lo;
    short8 ah[3], al[3];
    #pragma unroll
    for (int c = 0; c < 3; ++c) {
        ah[c] = *(const short8*)&sAh[m * ASTRIDE + c * 32 + quad * 8];
        al[c] = *(const short8*)&sAl[m * ASTRIDE + c * 32 + quad * 8];
    }
    #pragma unroll
    for (int i = 0; i < 6; ++i) {
        int e0 = (w * 6 + i) * 16;
        f32x4 acc = {0.f, 0.f, 0.f, 0.f};
        #pragma unroll
        for (int c = 0; c < 3; ++c) {
            size_t o = (size_t)(e0 + m) * 96 + c * 32 + quad * 8;
            short8 bh = *(const short8*)(wh + o);
            short8 bl = *(const short8*)(wl + o);
            acc = __builtin_amdgcn_mfma_f32_16x16x32_bf16(ah[c], bl, acc, 0, 0, 0);
            acc = __builtin_amdgcn_mfma_f32_16x16x32_bf16(al[c], bh, acc, 0, 0, 0);
            acc = __builtin_amdgcn_mfma_f32_16x16x32_bf16(ah[c], bh, acc, 0, 0, 0);
        }
        int e = e0 + m;
        #pragma unroll
        for (int r = 0; r < 4; ++r) {
            int p = p0 + quad * 4 + r;
            if (e < 192) xin[(size_t)p * 192 + e] = acc[r];
            else         zb[(size_t)p * 192 + (e - 192)] = f2bf(silu_f(acc[r]));
        }
    }
}

// depthwise 3x3, 8 pixels/block; full 3x10 window preloaded into registers.
__global__ __launch_bounds__(192) void k_conv8(
        const float* __restrict__ xin, const float* __restrict__ cw,
        const float* __restrict__ cb, float* __restrict__ xg) {
    int blk = blockIdx.x;             // 2048 = 4 b * 64 h * 8 wchunks
    int b = blk >> 9;
    int rem = blk & 511;
    int h = rem >> 3;
    int w0 = (rem & 7) * 8;
    int d = threadIdx.x;
    float wr[3][3];
    #pragma unroll
    for (int i = 0; i < 3; ++i)
        #pragma unroll
        for (int j = 0; j < 3; ++j) wr[i][j] = cw[d * 9 + i * 3 + j];
    float bias = cb[d];
    float r0[10], r1[10], r2[10];
    #pragma unroll
    for (int jj = 0; jj < 10; ++jj) {
        int ww = w0 + jj - 1;
        bool inw = (unsigned)ww < 64u;        // block-uniform
        const float* base = xin + ((size_t)b * 4096 + h * 64 + (inw ? ww : 0)) * 192 + d;
        r0[jj] = (inw && h > 0)  ? base[-64 * 192] : 0.0f;
        r1[jj] = inw             ? base[0]         : 0.0f;
        r2[jj] = (inw && h < 63) ? base[64 * 192]  : 0.0f;
    }
    float acc[8];
    #pragma unroll
    for (int o = 0; o < 8; ++o) {
        float a = bias;
        #pragma unroll
        for (int j = 0; j < 3; ++j) {
            a = fmaf(r0[o + j], wr[0][j], a);
            a = fmaf(r1[o + j], wr[1][j], a);
            a = fmaf(r2[o + j], wr[2][j], a);
        }
        acc[o] = a;
    }
    #pragma unroll
    for (int o = 0; o < 8; ++o) {
        int w = w0 + o;
        int kq = (h & 1) ? ((w & 1) ? 3 : 1) : ((w & 1) ? 2 : 0);
        int l = (kq & 1) ? ((w >> 1) * 32 + (h >> 1))
                         : ((h >> 1) * 32 + (w >> 1));
        xg[((size_t)(b * 4 + kq) * 1024 + l) * 192 + d] = silu_f(acc[o]);
    }
}

// Fused x_dbl MFMA + local scan (h_in = 0). One block per (bk, 16-l chunk).
// Staging keeps BOTH an fp32 sU copy (proven scan input) and the bf16 hi/lo
// split (MFMA A). MFMA body = k_xdbl verbatim, stores to LDS; dtr/Cm dumped
// for the proven k_scan3c. Scan body = k_scan1y verbatim.
__global__ __launch_bounds__(192) void k_xscan(
        const float* __restrict__ xg,
        const unsigned short* __restrict__ Xp_hi,
        const unsigned short* __restrict__ Xp_lo,
        const float* __restrict__ A_logs, const float* __restrict__ dtw,
        const float* __restrict__ dtb, const float* __restrict__ Ds,
        float* __restrict__ dtr, float* __restrict__ Cm,
        float* __restrict__ Sbuf, unsigned short* __restrict__ Qb,
        unsigned short* __restrict__ yout) {
    __shared__ __align__(16) short sAh[16 * XSTRIDE];
    __shared__ __align__(16) short sAl[16 * XSTRIDE];
    __shared__ __align__(16) float sU[CHUNK * USTRIDE];
    __shared__ float sB[CHUNK * 16];
    __shared__ float sC[CHUNK * 16];
    __shared__ float sDt[CHUNK * 6];

    int bk = blockIdx.x >> 6;
    int ch = blockIdx.x & 63;
    int k = bk & 3;
    int t = threadIdx.x;
    int d = t;
    int lbase = bk * 1024 + ch * CHUNK;

    // ---- stage u tile: fp32 sU + bf16 hi/lo split ----
    {
        const float4* us = (const float4*)(xg + (size_t)lbase * 192);
        for (int i = t; i < 768; i += 192) {     // 16*192 floats = 768 float4
            float4 v = us[i];
            int f = i * 4;
            int row = f / 192, col = f - row * 192;
            short4v hi, lo;
            unsigned short hb;
            hb = f2bf(v.x); hi.x = (short)hb; lo.x = (short)f2bf(v.x - bf2f(hb));
            hb = f2bf(v.y); hi.y = (short)hb; lo.y = (short)f2bf(v.y - bf2f(hb));
            hb = f2bf(v.z); hi.z = (short)hb; lo.z = (short)f2bf(v.z - bf2f(hb));
            hb = f2bf(v.w); hi.w = (short)hb; lo.w = (short)f2bf(v.w - bf2f(hb));
            *(short4v*)&sAh[row * XSTRIDE + col] = hi;
            *(short4v*)&sAl[row * XSTRIDE + col] = lo;
            *(float4*)&sU[row * USTRIDE + col] = v;
        }
    }
    __syncthreads();

    // ---- x_dbl MFMA (k_xdbl body), stores -> sDt/sB/sC ----
    {
        int wv = t >> 6;                  // N-tile 0..2
        int lane = t & 63;
        int m = lane & 15, quad = lane >> 4;
        const short* bh16 = (const short*)Xp_hi;
        const short* bl16 = (const short*)Xp_lo;
        int n0 = wv * 16;
        size_t brow = ((size_t)k * 48 + n0 + m) * 192;
        f32x4 acc = {0.f, 0.f, 0.f, 0.f};
        #pragma unroll
        for (int c = 0; c < 6; ++c) {
            short8 ah = *(const short8*)&sAh[m * XSTRIDE + c * 32 + quad * 8];
            short8 al = *(const short8*)&sAl[m * XSTRIDE + c * 32 + quad * 8];
            short8 bh = *(const short8*)(bh16 + brow + c * 32 + quad * 8);
            short8 bl = *(const short8*)(bl16 + brow + c * 32 + quad * 8);
            acc = __builtin_amdgcn_mfma_f32_16x16x32_bf16(ah, bl, acc, 0, 0, 0);
            acc = __builtin_amdgcn_mfma_f32_16x16x32_bf16(al, bh, acc, 0, 0, 0);
            acc = __builtin_amdgcn_mfma_f32_16x16x32_bf16(ah, bh, acc, 0, 0, 0);
        }
        int c = n0 + m;                   // output c-row
        #pragma unroll
        for (int r = 0; r < 4; ++r) {
            int ll = quad * 4 + r;
            float v = acc[r];
            if (c < 6)       sDt[ll * 6 + c] = v;
            else if (c < 22) sB[ll * 16 + (c - 6)] = v;
            else if (c < 38) sC[ll * 16 + (c - 22)] = v;
        }
    }
    __syncthreads();

    // ---- dump dtr / Cm for the proven k_scan3c ----
    if (t < 96) dtr[(size_t)(lbase + t / 6) * 6 + (t % 6)] = sDt[t];
    for (int i = t; i < CHUNK * 16; i += 192)
        Cm[(size_t)lbase * 16 + i] = sC[i];

    // ---- local scan (k_scan1y body; dlt from sDt, u from fp32 sU) ----
    {
        float A[16];
        #pragma unroll
        for (int n = 0; n < 16; ++n) A[n] = -__expf(A_logs[(k * 192 + d) * 16 + n]);
        float A0 = A[0];
        bool geo = true;                 // A[n] == (n+1)*A[0] (geometric ladder)?
        #pragma unroll
        for (int n = 1; n < 16; ++n)
            geo = geo && (fabsf(A[n] - (float)(n + 1) * A0) <= 1e-4f * fabsf(A[n]));
        float wp[6];
        #pragma unroll
        for (int q = 0; q < 6; ++q) wp[q] = dtw[(k * 192 + d) * 6 + q];
        float bias = dtb[k * 192 + d];
        float Dp = Ds[k * 192 + d];
        float dlt[CHUNK];
        #pragma unroll 4
        for (int l = 0; l < CHUNK; ++l) {
            float a = bias;
            #pragma unroll
            for (int q = 0; q < 6; ++q) a = fmaf(wp[q], sDt[l * 6 + q], a);
            dlt[l] = softplus_f(a);
        }
        float S = 0.0f;
        #pragma unroll
        for (int l = 0; l < CHUNK; ++l) S += dlt[l];
        float h[16];
        #pragma unroll
        for (int n = 0; n < 16; ++n) h[n] = 0.0f;
        if (geo) {
            float e1v[CHUNK];
            #pragma unroll 4
            for (int l = 0; l < CHUNK; ++l) e1v[l] = __expf(dlt[l] * A0);
            #pragma unroll 2
            for (int l = 0; l < CHUNK; ++l) {
                float u = sU[l * USTRIDE + d];
                float du = dlt[l] * u;
                float e1 = e1v[l];
                float e = e1;
                float y = 0.0f;
                #pragma unroll
                for (int n = 0; n < 16; ++n) {
                    h[n] = fmaf(e, h[n], du * sB[l * 16 + n]);
                    y = fmaf(h[n], sC[l * 16 + n], y);
                    e *= e1;
                }
                yout[(size_t)(lbase + l) * 192 + d] = f2bf(fmaf(u, Dp, y));
            }
        } else {
            for (int l = 0; l < CHUNK; ++l) {
                float u = sU[l * USTRIDE + d];
                float du = dlt[l] * u;
                float y = 0.0f;
                #pragma unroll
                for (int n = 0; n < 16; ++n) {
                    float e = __expf(dlt[l] * A[n]);
                    h[n] = fmaf(e, h[n], du * sB[l * 16 + n]);
                    y = fmaf(h[n], sC[l * 16 + n], y);
                }
                yout[(size_t)(lbase + l) * 192 + d] = f2bf(fmaf(u, Dp, y));
            }
        }
        Sbuf[(size_t)ch * SSTRIDE + bk * 192 + d] = S;
        size_t base = (size_t)ch * NSTATES + bk * (192 * 16);
        #pragma unroll
        for (int n = 0; n < 16; ++n)
            Qb[base + n * 192 + d] = f2bf(h[n]);
    }
}

// Pass 2: prefix over chunks; P = exp(A*S). 8x-batched. Hst bf16. [proven]
__global__ __launch_bounds__(256) void k_scan2(
        const float* __restrict__ Sbuf, const float* __restrict__ A_logs,
        const unsigned short* __restrict__ Qb, unsigned short* __restrict__ Hst) {
    int s = blockIdx.x * 256 + threadIdx.x;   // 0..NSTATES-1
    int bk = s / 3072;                         // 3072 = 16*192
    int rem = s - bk * 3072;
    int n = rem / 192;
    int d = rem - n * 192;
    int k = bk & 3;
    float A = -__expf(A_logs[(k * 192 + d) * 16 + n]);
    int sb = bk * 192 + d;
    float h = 0.0f;
    for (int c0 = 0; c0 < NCH; c0 += 8) {
        float Sv[8], qv[8], pv[8];
        #pragma unroll
        for (int j = 0; j < 8; ++j) {
            Sv[j] = Sbuf[(size_t)(c0 + j) * SSTRIDE + sb];
            qv[j] = bf2f(Qb[(size_t)(c0 + j) * NSTATES + s]);
        }
        #pragma unroll
        for (int j = 0; j < 8; ++j) pv[j] = __expf(A * Sv[j]);
        #pragma unroll
        for (int j = 0; j < 8; ++j) {
            Hst[(size_t)(c0 + j) * NSTATES + s] = f2bf(h);
            h = fmaf(pv[j], h, qv[j]);
        }
    }
}

// Pass 3: chain-free correction on bf16 yout; decays precomputed. [proven]
__global__ __launch_bounds__(192) void k_scan3c(
        const float* __restrict__ dtr, const float* __restrict__ Cm,
        const float* __restrict__ A_logs, const float* __restrict__ dtw,
        const float* __restrict__ dtb, const unsigned short* __restrict__ Hst,
        unsigned short* __restrict__ yout) {
    __shared__ float sC[CHUNK * 16];
    int bk = blockIdx.x >> 6;
    int ch = blockIdx.x & 63;
    if (ch == 0) return;              // h0 == 0, no correction
    int k = bk & 3;
    int d = threadIdx.x;
    int lbase = bk * 1024 + ch * CHUNK;
    for (int i = d; i < CHUNK * 16; i += 192)
        sC[i] = Cm[(size_t)lbase * 16 + i];
    float A[16];
    #pragma unroll
    for (int n = 0; n < 16; ++n) A[n] = -__expf(A_logs[(k * 192 + d) * 16 + n]);
    float A0 = A[0];
    bool geo = true;
    #pragma unroll
    for (int n = 1; n < 16; ++n)
        geo = geo && (fabsf(A[n] - (float)(n + 1) * A0) <= 1e-4f * fabsf(A[n]));
    float wp[6];
    #pragma unroll
    for (int q = 0; q < 6; ++q) wp[q] = dtw[(k * 192 + d) * 6 + q];
    float bias = dtb[k * 192 + d];
    float h0[16];
    size_t base = (size_t)ch * NSTATES + bk * (192 * 16);
    #pragma unroll
    for (int n = 0; n < 16; ++n) h0[n] = bf2f(Hst[base + n * 192 + d]);
    float Sarr[CHUNK];
    {
        float S = 0.0f;
        #pragma unroll 4
        for (int l = 0; l < CHUNK; ++l) {
            const float* r = dtr + (size_t)(lbase + l) * 6;   // wave-uniform
            float a = bias;
            #pragma unroll
            for (int q = 0; q < 6; ++q) a = fmaf(wp[q], r[q], a);
            S += softplus_f(a);
            Sarr[l] = S;
        }
    }
    __syncthreads();
    if (geo) {
        float e1l[CHUNK];
        #pragma unroll 4
        for (int l = 0; l < CHUNK; ++l) e1l[l] = __expf(A0 * Sarr[l]);
        #pragma unroll 2
        for (int l = 0; l < CHUNK; ++l) {
            float y = bf2f(yout[(size_t)(lbase + l) * 192 + d]);
            float e1 = e1l[l];
            float e = e1;
            float corr = 0.0f;
            #pragma unroll
            for (int n = 0; n < 16; ++n) {
                corr = fmaf(h0[n] * e, sC[l * 16 + n], corr);
                e *= e1;
            }
            yout[(size_t)(lbase + l) * 192 + d] = f2bf(y + corr);
        }
    } else {
        for (int l = 0; l < CHUNK; ++l) {
            float y = bf2f(yout[(size_t)(lbase + l) * 192 + d]);
            float corr = 0.0f;
            #pragma unroll
            for (int n = 0; n < 16; ++n) {
                float e = __expf(A[n] * Sarr[l]);
                corr = fmaf(h0[n] * e, sC[l * 16 + n], corr);
            }
            yout[(size_t)(lbase + l) * 192 + d] = f2bf(y + corr);
        }
    }
}

// merge + LayerNorm + gate (bf16 z) -> g (bf16, LDS) -> MFMA out GEMM. [proven]
__global__ __launch_bounds__(256) void k_lnout(
        const unsigned short* __restrict__ yout,
        const unsigned short* __restrict__ zb,
        const float* __restrict__ lng, const float* __restrict__ lnb,
        const unsigned short* __restrict__ Wo_bf, float* __restrict__ out) {
    __shared__ __align__(16) short sgb[32 * GSTRIDE];
    int p0 = blockIdx.x * 32;
    int t = threadIdx.x;
    int p = t >> 3;                    // pixel 0..31
    int sub = t & 7;                   // 8 threads per pixel, 24 channels each
    int gp = p0 + p;
    int b = gp >> 12;
    int hw = gp & 4095;
    int h = hw >> 6, w = hw & 63;
    int kq = (h & 1) ? ((w & 1) ? 3 : 1) : ((w & 1) ? 2 : 0);
    int l = (kq & 1) ? ((w >> 1) * 32 + (h >> 1))
                     : ((h >> 1) * 32 + (w >> 1));
    const unsigned short* yrow =
        yout + ((size_t)(b * 4 + kq) * 1024 + l) * 192 + sub * 24;
    float yv[24];
    float s = 0.0f, s2 = 0.0f;
    #pragma unroll
    for (int j = 0; j < 3; ++j) {
        ushort8v v8 = *(const ushort8v*)(yrow + j * 8);
        #pragma unroll
        for (int e = 0; e < 8; ++e) {
            float v = bf2f(v8[e]);
            yv[j * 8 + e] = v;
            s += v;
            s2 += v * v;
        }
    }
    #pragma unroll
    for (int off = 1; off < 8; off <<= 1) {
        s  += __shfl_xor(s, off, 8);
        s2 += __shfl_xor(s2, off, 8);
    }
    float mu = s * (1.0f / 192.0f);
    float var = s2 * (1.0f / 192.0f) - mu * mu;
    float rstd = rsqrtf(var + 1e-5f);
    const unsigned short* zrow = zb + (size_t)gp * 192 + sub * 24;
    short* grow = sgb + p * GSTRIDE + sub * 24;
    #pragma unroll
    for (int j = 0; j < 6; ++j) {
        ushort4v zv4 = *(const ushort4v*)(zrow + j * 4);
        float4 gv = *(const float4*)(lng + sub * 24 + j * 4);
        float4 bv = *(const float4*)(lnb + sub * 24 + j * 4);
        short4v sv;
        sv.x = (short)f2bf(((yv[j * 4 + 0] - mu) * rstd * gv.x + bv.x) * bf2f(zv4.x));
        sv.y = (short)f2bf(((yv[j * 4 + 1] - mu) * rstd * gv.y + bv.y) * bf2f(zv4.y));
        sv.z = (short)f2bf(((yv[j * 4 + 2] - mu) * rstd * gv.z + bv.z) * bf2f(zv4.z));
        sv.w = (short)f2bf(((yv[j * 4 + 3] - mu) * rstd * gv.w + bv.w) * bf2f(zv4.w));
        *(short4v*)(grow + j * 4) = sv;
    }
    __syncthreads();
    int wv = t >> 6;
    int lane = t & 63;
    int m = lane & 15, quad = lane >> 4;
    int mt = wv >> 1;
    int nb = (wv & 1) * 3;
    const short* wob = (const short*)Wo_bf;
    short8 a[6];
    #pragma unroll
    for (int kk = 0; kk < 6; ++kk)
        a[kk] = *(const short8*)(sgb + (mt * 16 + m) * GSTRIDE + kk * 32 + quad * 8);
    #pragma unroll
    for (int i = 0; i < 3; ++i) {
        int n0 = (nb + i) * 16;
        f32x4 acc = {0.f, 0.f, 0.f, 0.f};
        #pragma unroll
        for (int kk = 0; kk < 6; ++kk) {
            short8 bfr = *(const short8*)(wob + (size_t)(n0 + m) * 192 + kk * 32 + quad * 8);
            acc = __builtin_amdgcn_mfma_f32_16x16x32_bf16(a[kk], bfr, acc, 0, 0, 0);
        }
        #pragma unroll
        for (int r = 0; r < 4; ++r) {
            int pp = p0 + mt * 16 + quad * 4 + r;
            out[(size_t)pp * 96 + n0 + m] = acc[r];
        }
    }
}

extern "C" void kernel_launch(void* const* d_in, const int* in_sizes, int n_in,
                              void* d_out, int out_size, void* d_ws, size_t ws_size,
                              hipStream_t stream) {
    const float* x    = (const float*)d_in[0];
    const float* W_in = (const float*)d_in[1];
    const float* cw   = (const float*)d_in[2];
    const float* cb   = (const float*)d_in[3];
    const float* xpw  = (const float*)d_in[4];
    const float* dtw  = (const float*)d_in[5];
    const float* dtb  = (const float*)d_in[6];
    const float* Alog = (const float*)d_in[7];
    const float* Ds   = (const float*)d_in[8];
    const float* lng  = (const float*)d_in[9];
    const float* lnb  = (const float*)d_in[10];
    const float* Wout = (const float*)d_in[11];
    float* out = (float*)d_out;

    float* ws = (float*)d_ws;
    size_t off = 0;
    unsigned short* Wi_hi = (unsigned short*)(ws + off); off += 384 * 96 / 2;
    unsigned short* Wi_lo = (unsigned short*)(ws + off); off += 384 * 96 / 2;
    unsigned short* Xp_hi = (unsigned short*)(ws + off); off += 4 * 48 * 192 / 2;
    unsigned short* Xp_lo = (unsigned short*)(ws + off); off += 4 * 48 * 192 / 2;
    unsigned short* Wo_bf = (unsigned short*)(ws + off); off += 96 * DINNER / 2;
    float* xin   = ws + off; off += (size_t)NPIX * 192;
    unsigned short* zb = (unsigned short*)(ws + off); off += (size_t)NPIX * 192 / 2;
    float* xg    = ws + off; off += (size_t)NPIX * 192;
    float* dtrb  = ws + off; off += (size_t)NBK * LP * 6;
    float* Cm    = ws + off; off += (size_t)NBK * LP * 16;
    float* Sbuf  = ws + off; off += (size_t)NCH * SSTRIDE;
    unsigned short* Qb  = (unsigned short*)(ws + off); off += (size_t)NCH * NSTATES / 2;
    unsigned short* Hst = (unsigned short*)(ws + off); off += (size_t)NCH * NSTATES / 2;
    unsigned short* yout = (unsigned short*)(ws + off); off += (size_t)NBK * LP * 192 / 2;

    hipLaunchKernelGGL(k_castW, dim3(144), dim3(256), 0, stream,
                       W_in, xpw, Wout, Wi_hi, Wi_lo, Xp_hi, Xp_lo, Wo_bf);
    hipLaunchKernelGGL(k_inproj3, dim3(NPIX / 16), dim3(256), 0, stream,
                       x, Wi_hi, Wi_lo, xin, zb);
    hipLaunchKernelGGL(k_conv8, dim3(NPIX / 8), dim3(192), 0, stream,
                       xin, cw, cb, xg);
    hipLaunchKernelGGL(k_xscan, dim3(NBK * NCH), dim3(192), 0, stream,
                       xg, Xp_hi, Xp_lo, Alog, dtw, dtb, Ds,
                       dtrb, Cm, Sbuf, Qb, yout);
    hipLaunchKernelGGL(k_scan2, dim3(NSTATES / 256), dim3(256), 0, stream,
                       Sbuf, Alog, Qb, Hst);
    hipLaunchKernelGGL(k_scan3c, dim3(NBK * NCH), dim3(192), 0, stream,
                       dtrb, Cm, Alog, dtw, dtb, Hst, yout);
    hipLaunchKernelGGL(k_lnout, dim3(NPIX / 32), dim3(256), 0, stream,
                       yout, zb, lng, lnb, Wo_bf, out);
}